// Round 12
// baseline (147.446 us; speedup 1.0000x reference)
//
#include <hip/hip_runtime.h>
#include <math.h>

using short8v = __attribute__((ext_vector_type(8))) short;
using f32x4   = __attribute__((ext_vector_type(4))) float;

constexpr int BCAP = 8192;  // per-bucket capacity (mean 4096, >60 sigma headroom)

// ---------------- bf16 helpers ----------------

__device__ inline float bf_lo(unsigned int p) { return __uint_as_float(p << 16); }
__device__ inline float bf_hi(unsigned int p) { return __uint_as_float(p & 0xffff0000u); }
__device__ inline float bf2f(unsigned short s) { return __uint_as_float(((unsigned int)s) << 16); }
__device__ inline unsigned short f2bf(float f) {  // round-to-nearest-even
    unsigned int u = __float_as_uint(f);
    u += 0x7fffu + ((u >> 16) & 1u);
    return (unsigned short)(u >> 16);
}

// ---------------- prep: init bucket cursors (1 block) ----------------

__global__ __launch_bounds__(256)
void prep_kernel(int* __restrict__ bcur, int nb) {
    int i = threadIdx.x;
    if (i < nb) bcur[i] = i * BCAP;
}

// ---------------- partition: bucket edges by dst>>8 into fixed-capacity regions ----------------

__global__ __launch_bounds__(1024)
void partA_kernel(const int* __restrict__ src, const int* __restrict__ dst,
                  int* __restrict__ bcur, int2* __restrict__ tmp, int E) {
    __shared__ int hist[256];
    __shared__ int chunk[256];
    int t = threadIdx.x;
    if (t < 256) hist[t] = 0;
    __syncthreads();
    int i = blockIdx.x * 1024 + t;
    int s = 0, d = 0, b = 0, lr = 0;
    bool valid = i < E;
    if (valid) {
        s = src[i];
        d = dst[i];
        b = d >> 8;
        lr = atomicAdd(&hist[b], 1);  // LDS atomic: local rank within (block,bucket)
    }
    __syncthreads();
    if (t < 256) {
        int c = hist[t];
        chunk[t] = (c > 0) ? atomicAdd(&bcur[t], c) : 0;
    }
    __syncthreads();
    if (valid) {
        tmp[chunk[b] + lr] = make_int2(s, d);
    }
}

// ---------------- bscan: bucket counts -> exact CSR bucket bases (1 block) ----------------

__global__ __launch_bounds__(256)
void bscan_kernel(const int* __restrict__ bcur, int* __restrict__ ebase,
                  int* __restrict__ rowptr, int nb, int N, int E) {
    __shared__ int s[256];
    int t = threadIdx.x;
    int v = (t < nb) ? (bcur[t] - t * BCAP) : 0;
    s[t] = v;
    __syncthreads();
    for (int off = 1; off < 256; off <<= 1) {
        int u = (t >= off) ? s[t - off] : 0;
        __syncthreads();
        s[t] += u;
        __syncthreads();
    }
    if (t < nb) ebase[t] = s[t] - v;  // exclusive
    if (t == 0) rowptr[N] = E;
}

// ---------------- bucket_build: per-bucket CSR + dinv + prescaled z (zs = dinv*z bf16) ----------------

__global__ __launch_bounds__(256)
void bucket_build_kernel(const int2* __restrict__ tmp, const int* __restrict__ bcur,
                         const int* __restrict__ ebase, const float* __restrict__ z,
                         int* __restrict__ rowptr, float* __restrict__ dinv,
                         int* __restrict__ col, unsigned int* __restrict__ zsb, int N) {
    __shared__ int h[256];
    __shared__ int sc[256];
    __shared__ int cur[256];
    __shared__ float sdv[256];
    int b = blockIdx.x;
    int t = threadIdx.x;
    int base = b * BCAP;
    int ecnt = bcur[b] - base;
    int eb = ebase[b];
    h[t] = 0;
    __syncthreads();
    for (int i = t; i < ecnt; i += 256) {
        atomicAdd(&h[tmp[base + i].y & 255], 1);
    }
    __syncthreads();
    int v = h[t];
    sc[t] = v;
    __syncthreads();
    for (int off = 1; off < 256; off <<= 1) {
        int u = (t >= off) ? sc[t - off] : 0;
        __syncthreads();
        sc[t] += u;
        __syncthreads();
    }
    int excl = sc[t] - v;
    int nd = b * 256 + t;
    float dv = rsqrtf((float)v + 1.0f);  // degree incl. self-loop
    if (nd < N) {
        rowptr[nd] = eb + excl;
        dinv[nd] = dv;
    }
    sdv[t] = dv;
    cur[t] = excl;
    __syncthreads();
    // scatter col (LDS cursors, contiguous window)
    for (int i = t; i < ecnt; i += 256) {
        int2 e = tmp[base + i];
        int lpos = atomicAdd(&cur[e.y & 255], 1);
        col[eb + lpos] = e.x;
    }
    // prescale this block's 256 z-rows: zs = bf16(dinv * z), packed pairs (32 uints/row)
    int nd0 = b * 256;
    for (int idx = t; idx < 256 * 32; idx += 256) {
        int row = idx >> 5;
        int p = idx & 31;
        int node = nd0 + row;
        if (node < N) {
            float2 zv = ((const float2*)z)[(size_t)node * 32 + p];
            float d = sdv[row];
            zsb[(size_t)node * 32 + p] =
                (unsigned int)f2bf(d * zv.x) | ((unsigned int)f2bf(d * zv.y) << 16);
        }
    }
}

// ---------------- aggregation: out[i] = dinv[i]*(xs[i] + sum_e xs[c]),  xs = dinv.*x ----

// layer 1: bf16 zs gather (64 feats = 1 ushort/lane), bf16 output (a1)
__global__ __launch_bounds__(256)
void agg64_kernel(const unsigned short* __restrict__ xs, const int* __restrict__ rowptr,
                  const int* __restrict__ col, const float* __restrict__ dinv,
                  unsigned short* __restrict__ out, int n) {
    int wid = (blockIdx.x * 256 + threadIdx.x) >> 6;
    int lane = threadIdx.x & 63;
    if (wid >= n) return;
    int i = __builtin_amdgcn_readfirstlane(wid);
    int beg = rowptr[i];
    int end = rowptr[i + 1];
    float di = dinv[i];
    float acc = bf2f(xs[(size_t)i * 64 + lane]);
    int e = beg;
    for (; e + 7 < end; e += 8) {
        int c0 = col[e], c1 = col[e + 1], c2 = col[e + 2], c3 = col[e + 3];
        int c4 = col[e + 4], c5 = col[e + 5], c6 = col[e + 6], c7 = col[e + 7];
        float v0 = bf2f(xs[(size_t)c0 * 64 + lane]);
        float v1 = bf2f(xs[(size_t)c1 * 64 + lane]);
        float v2 = bf2f(xs[(size_t)c2 * 64 + lane]);
        float v3 = bf2f(xs[(size_t)c3 * 64 + lane]);
        float v4 = bf2f(xs[(size_t)c4 * 64 + lane]);
        float v5 = bf2f(xs[(size_t)c5 * 64 + lane]);
        float v6 = bf2f(xs[(size_t)c6 * 64 + lane]);
        float v7 = bf2f(xs[(size_t)c7 * 64 + lane]);
        acc += v0; acc += v1; acc += v2; acc += v3;
        acc += v4; acc += v5; acc += v6; acc += v7;
    }
    for (; e < end; ++e) {
        acc += bf2f(xs[(size_t)col[e] * 64 + lane]);
    }
    out[(size_t)i * 64 + lane] = f2bf(di * acc);
}

// layer 2: bf16 hs gather (128 feats = 64 lanes x packed pair), bf16 output (a2)
__global__ __launch_bounds__(256)
void agg128_bf16_kernel(const unsigned int* __restrict__ xs2, const int* __restrict__ rowptr,
                        const int* __restrict__ col, const float* __restrict__ dinv,
                        unsigned int* __restrict__ out, int n) {
    int wid = (blockIdx.x * 256 + threadIdx.x) >> 6;
    int lane = threadIdx.x & 63;
    if (wid >= n) return;
    int i = __builtin_amdgcn_readfirstlane(wid);
    int beg = rowptr[i];
    int end = rowptr[i + 1];
    float di = dinv[i];
    unsigned int sp = xs2[(size_t)i * 64 + lane];
    float accx = bf_lo(sp);
    float accy = bf_hi(sp);
    int e = beg;
    for (; e + 7 < end; e += 8) {
        int c0 = col[e], c1 = col[e + 1], c2 = col[e + 2], c3 = col[e + 3];
        int c4 = col[e + 4], c5 = col[e + 5], c6 = col[e + 6], c7 = col[e + 7];
        unsigned int p0 = xs2[(size_t)c0 * 64 + lane];
        unsigned int p1 = xs2[(size_t)c1 * 64 + lane];
        unsigned int p2 = xs2[(size_t)c2 * 64 + lane];
        unsigned int p3 = xs2[(size_t)c3 * 64 + lane];
        unsigned int p4 = xs2[(size_t)c4 * 64 + lane];
        unsigned int p5 = xs2[(size_t)c5 * 64 + lane];
        unsigned int p6 = xs2[(size_t)c6 * 64 + lane];
        unsigned int p7 = xs2[(size_t)c7 * 64 + lane];
        accx += bf_lo(p0); accy += bf_hi(p0);
        accx += bf_lo(p1); accy += bf_hi(p1);
        accx += bf_lo(p2); accy += bf_hi(p2);
        accx += bf_lo(p3); accy += bf_hi(p3);
        accx += bf_lo(p4); accy += bf_hi(p4);
        accx += bf_lo(p5); accy += bf_hi(p5);
        accx += bf_lo(p6); accy += bf_hi(p6);
        accx += bf_lo(p7); accy += bf_hi(p7);
    }
    for (; e < end; ++e) {
        unsigned int p = xs2[(size_t)col[e] * 64 + lane];
        accx += bf_lo(p);
        accy += bf_hi(p);
    }
    unsigned int o = (unsigned int)f2bf(di * accx) | ((unsigned int)f2bf(di * accy) << 16);
    out[(size_t)i * 64 + lane] = o;
}

// ---------------- MFMA GEMM: C[n,128] = A[n,K](bf16) @ W[K,128](fp32->bf16) + b ----------------
// DSCALE: epilogue multiplies by dinv[row] (producing prescaled hs for layer-2 agg).
// mfma_f32_16x16x32_bf16: A-frag lane l: row=l&15, k=(l>>4)*8+j ; B-frag: col=l&15, k=(l>>4)*8+j ;
// C/D: col=lane&15, row=(lane>>4)*4+reg  [m89-verified].

template <int K, int BF16OUT, int DSCALE>
__global__ __launch_bounds__(256)
void gemm_mfma_kernel(const unsigned short* __restrict__ A, const float* __restrict__ W,
                      const float* __restrict__ bias, const float* __restrict__ dinv,
                      void* __restrict__ C, int n, int ntiles, int do_relu) {
    constexpr int KK = K / 32;
    __shared__ short sB[8 * KK * 64 * 8];  // = K*128 bf16, frag-major
    int t = threadIdx.x;
    constexpr int total = 8 * KK * 64 * 8;
    for (int e = t; e < total; e += 256) {
        int j = e & 7;
        int l = (e >> 3) & 63;
        int rest = e >> 9;          // c*KK + kk
        int kk = rest % KK;
        int c = rest / KK;
        int rk = kk * 32 + (l >> 4) * 8 + j;
        int cc = c * 16 + (l & 15);
        sB[e] = (short)f2bf(W[rk * 128 + cc]);
    }
    __syncthreads();

    int wid = t >> 6;
    int l = t & 63;
    int tile = blockIdx.x * 4 + wid;
    if (tile >= ntiles) return;
    int r0 = tile * 16;

    const short8v* sB8 = (const short8v*)sB;
    f32x4 acc[8];
#pragma unroll
    for (int c = 0; c < 8; ++c) acc[c] = (f32x4){0.0f, 0.0f, 0.0f, 0.0f};

    int arow = r0 + (l & 15);
    if (arow >= n) arow = n - 1;  // clamp (guard at store)
#pragma unroll
    for (int kk = 0; kk < KK; ++kk) {
        short8v av = *(const short8v*)(A + (size_t)arow * K + kk * 32 + (l >> 4) * 8);
#pragma unroll
        for (int c = 0; c < 8; ++c) {
            acc[c] = __builtin_amdgcn_mfma_f32_16x16x32_bf16(av, sB8[(c * KK + kk) * 64 + l],
                                                             acc[c], 0, 0, 0);
        }
    }

    int colbase = l & 15;
    int rowg = (l >> 4) * 4;
    float dvj[4] = {1.0f, 1.0f, 1.0f, 1.0f};
    if (DSCALE) {
#pragma unroll
        for (int j = 0; j < 4; ++j) {
            int row = r0 + rowg + j;
            dvj[j] = (row < n) ? dinv[row] : 1.0f;
        }
    }
#pragma unroll
    for (int c = 0; c < 8; ++c) {
        float bv = bias[c * 16 + colbase];
#pragma unroll
        for (int j = 0; j < 4; ++j) {
            int row = r0 + rowg + j;
            if (row < n) {
                float v = acc[c][j] + bv;
                if (do_relu) v = fmaxf(v, 0.0f);
                if (DSCALE) v *= dvj[j];
                if (BF16OUT)
                    ((unsigned short*)C)[(size_t)row * 128 + c * 16 + colbase] = f2bf(v);
                else
                    ((float*)C)[(size_t)row * 128 + c * 16 + colbase] = v;
            }
        }
    }
}

// ---------------- launch ----------------

extern "C" void kernel_launch(void* const* d_in, const int* in_sizes, int n_in,
                              void* d_out, int out_size, void* d_ws, size_t ws_size,
                              hipStream_t stream) {
    const float* z  = (const float*)d_in[0];
    const int*   ei = (const int*)d_in[1];
    const float* W1 = (const float*)d_in[2];
    const float* b1 = (const float*)d_in[3];
    const float* W2 = (const float*)d_in[4];
    const float* b2 = (const float*)d_in[5];
    float* out = (float*)d_out;

    int N = in_sizes[0] / 64;
    int E = in_sizes[1] / 2;
    const int* srcp = ei;
    const int* dstp = ei + E;

    char* w = (char*)d_ws;
    auto alloc = [&](size_t bytes) -> char* {
        char* p = w;
        w += (bytes + 255) & ~(size_t)255;
        return p;
    };
    int nb = (N + 255) / 256;  // 196 for N=50000 (must be <= 256)

    int*   rowptr = (int*)alloc((size_t)(N + 1) * 4);
    float* dinv   = (float*)alloc((size_t)N * 4);
    int*   bcur   = (int*)alloc((size_t)nb * 4);
    int*   ebase  = (int*)alloc((size_t)nb * 4);
    int*   col    = (int*)alloc((size_t)E * 4);
    int2*  tmp    = (int2*)alloc((size_t)nb * BCAP * 8);
    unsigned int*   zsb = (unsigned int*)alloc((size_t)N * 64 * 2);     // bf16 zs = dinv*z (packed)
    unsigned short* a1b = (unsigned short*)alloc((size_t)N * 64 * 2);   // bf16 a1
    unsigned short* hsb = (unsigned short*)alloc((size_t)N * 128 * 2);  // bf16 hs = dinv*h
    unsigned int*   a2b = (unsigned int*)alloc((size_t)N * 128 * 2);    // bf16 a2 (packed pairs)

    // CSR build + prescaled z (4 dispatches)
    prep_kernel<<<1, 256, 0, stream>>>(bcur, nb);
    partA_kernel<<<(E + 1023) / 1024, 1024, 0, stream>>>(srcp, dstp, bcur, tmp, E);
    bscan_kernel<<<1, 256, 0, stream>>>(bcur, ebase, rowptr, nb, N, E);
    bucket_build_kernel<<<nb, 256, 0, stream>>>(tmp, bcur, ebase, z, rowptr, dinv, col, zsb, N);

    int aggBlocks = (int)(((size_t)N * 64 + 255) / 256);
    int ntiles = (N + 15) / 16;           // 3125 for N=50000
    int gemmBlocks = (ntiles + 3) / 4;    // 4 waves (tiles) per block

    // layer 1: a1b = bf16(Agg(zs)) [N,64]; hsb = bf16(dinv .* relu(a1b @ W1 + b1)) [N,128]
    agg64_kernel<<<aggBlocks, 256, 0, stream>>>((const unsigned short*)zsb, rowptr, col, dinv, a1b, N);
    gemm_mfma_kernel<64, 1, 1><<<gemmBlocks, 256, 0, stream>>>(a1b, W1, b1, dinv, (void*)hsb, N, ntiles, 1);

    // layer 2: a2b = bf16(Agg(hs)) [N,128]; out = a2b @ W2 + b2 (fp32)
    agg128_bf16_kernel<<<aggBlocks, 256, 0, stream>>>((const unsigned int*)hsb, rowptr, col, dinv, a2b, N);
    gemm_mfma_kernel<128, 0, 0><<<gemmBlocks, 256, 0, stream>>>((const unsigned short*)a2b, W2, b2, dinv,
                                                                (void*)out, N, ntiles, 0);
}

// Round 13
// 140.890 us; speedup vs baseline: 1.0465x; 1.0465x over previous
//
#include <hip/hip_runtime.h>
#include <math.h>

using short8v = __attribute__((ext_vector_type(8))) short;
using f32x4   = __attribute__((ext_vector_type(4))) float;

constexpr int BCAP = 8192;  // per-bucket capacity (mean ~4081, >60 sigma headroom)

// ---------------- bf16 helpers ----------------

__device__ inline float bf_lo(unsigned int p) { return __uint_as_float(p << 16); }
__device__ inline float bf_hi(unsigned int p) { return __uint_as_float(p & 0xffff0000u); }
__device__ inline unsigned short f2bf(float f) {  // round-to-nearest-even
    unsigned int u = __float_as_uint(f);
    u += 0x7fffu + ((u >> 16) & 1u);
    return (unsigned short)(u >> 16);
}
__device__ inline unsigned int pack2bf(float a, float b) {
    return (unsigned int)f2bf(a) | ((unsigned int)f2bf(b) << 16);
}

// ---------------- prep: init bucket cursors (1 block) ----------------

__global__ __launch_bounds__(256)
void prep_kernel(int* __restrict__ bcur, int nb) {
    int i = threadIdx.x;
    if (i < nb) bcur[i] = i * BCAP;
}

// ---------------- partition: bucket edges by dst>>8; 4096 edges/block ----------------

__global__ __launch_bounds__(1024)
void partA_kernel(const int* __restrict__ src, const int* __restrict__ dst,
                  int* __restrict__ bcur, int2* __restrict__ tmp, int E) {
    __shared__ int hist[256];
    __shared__ int chunk[256];
    int t = threadIdx.x;
    if (t < 256) hist[t] = 0;
    __syncthreads();
    int base = blockIdx.x * 4096;
    int s[4], d[4], bb[4], lr[4];
    bool val[4];
#pragma unroll
    for (int k = 0; k < 4; ++k) {
        int i = base + k * 1024 + t;
        val[k] = i < E;
        if (val[k]) {
            s[k] = src[i];
            d[k] = dst[i];
            bb[k] = d[k] >> 8;
            lr[k] = atomicAdd(&hist[bb[k]], 1);  // LDS: local rank in (block,bucket)
        }
    }
    __syncthreads();
    if (t < 256) {
        int c = hist[t];
        chunk[t] = (c > 0) ? atomicAdd(&bcur[t], c) : 0;
    }
    __syncthreads();
#pragma unroll
    for (int k = 0; k < 4; ++k) {
        if (val[k]) tmp[chunk[bb[k]] + lr[k]] = make_int2(s[k], d[k]);
    }
}

// ------- bucket_build: folded bucket-scan + per-bucket CSR + dinv + prescaled z -------

__global__ __launch_bounds__(256)
void bucket_build_kernel(const int2* __restrict__ tmp, const int* __restrict__ bcur,
                         const float* __restrict__ z, int* __restrict__ rowptr,
                         float* __restrict__ dinv, int* __restrict__ col,
                         unsigned int* __restrict__ zsb, int N, int nb, int E) {
    __shared__ int s[256];
    __shared__ int h[256];
    __shared__ int sc[256];
    __shared__ int cur[256];
    __shared__ float sdv[256];
    __shared__ int s_eb;
    int b = blockIdx.x;
    int t = threadIdx.x;
    // folded bscan: every block scans all bucket counts (196 ints, trivial)
    int cnt_t = (t < nb) ? (bcur[t] - t * BCAP) : 0;
    s[t] = cnt_t;
    __syncthreads();
    for (int off = 1; off < 256; off <<= 1) {
        int u = (t >= off) ? s[t - off] : 0;
        __syncthreads();
        s[t] += u;
        __syncthreads();
    }
    if (t == b) s_eb = s[t] - cnt_t;  // exclusive prefix for this bucket
    if (b == 0 && t == 0) rowptr[N] = E;
    h[t] = 0;
    __syncthreads();
    int eb = s_eb;
    int base = b * BCAP;
    int ecnt = bcur[b] - base;
    // per-node histogram
    for (int i = t; i < ecnt; i += 256) {
        atomicAdd(&h[tmp[base + i].y & 255], 1);
    }
    __syncthreads();
    int v = h[t];
    sc[t] = v;
    __syncthreads();
    for (int off = 1; off < 256; off <<= 1) {
        int u = (t >= off) ? sc[t - off] : 0;
        __syncthreads();
        sc[t] += u;
        __syncthreads();
    }
    int excl = sc[t] - v;
    int nd = b * 256 + t;
    float dv = rsqrtf((float)v + 1.0f);  // degree incl. self-loop
    if (nd < N) {
        rowptr[nd] = eb + excl;
        dinv[nd] = dv;
    }
    sdv[t] = dv;
    cur[t] = excl;
    __syncthreads();
    // scatter col (LDS cursors, contiguous window)
    for (int i = t; i < ecnt; i += 256) {
        int2 e = tmp[base + i];
        int lpos = atomicAdd(&cur[e.y & 255], 1);
        col[eb + lpos] = e.x;
    }
    // prescale this block's 256 z-rows: zs = bf16(dinv * z), packed pairs (32 uints/row)
    int nd0 = b * 256;
    for (int idx = t; idx < 256 * 32; idx += 256) {
        int row = idx >> 5;
        int p = idx & 31;
        int node = nd0 + row;
        if (node < N) {
            float2 zv = ((const float2*)z)[(size_t)node * 32 + p];
            float d = sdv[row];
            zsb[(size_t)node * 32 + p] = pack2bf(d * zv.x, d * zv.y);
        }
    }
}

// ------- aggregation: out[i] = dinv[i]*(xs[i] + sum_e xs[c]),  xs = dinv.*x -------
// Half-wave dual-row gathers: lanes 0-31 take even edges, 32-63 odd edges;
// per-lane partial sums merged once at the end via shfl_xor(32).

// layer 1: 64 feats = 32 lanes x packed bf16 pair; 8 rows in flight per wave
__global__ __launch_bounds__(256)
void agg64_kernel(const unsigned int* __restrict__ xs2, const int* __restrict__ rowptr,
                  const int* __restrict__ col, const float* __restrict__ dinv,
                  unsigned int* __restrict__ out2, int n) {
    int wid = (blockIdx.x * 256 + threadIdx.x) >> 6;
    int lane = threadIdx.x & 63;
    if (wid >= n) return;
    int i = __builtin_amdgcn_readfirstlane(wid);
    int half = lane >> 5;
    int sl = lane & 31;
    int beg = rowptr[i];
    int end = rowptr[i + 1];
    float di = dinv[i];
    float ax = 0.0f, ay = 0.0f;
    if (half == 0) {
        unsigned int sp = xs2[(size_t)i * 32 + sl];
        ax = bf_lo(sp);
        ay = bf_hi(sp);
    }
    int e = beg;
    for (; e + 7 < end; e += 8) {
        int c0 = col[e + half];
        int c1 = col[e + 2 + half];
        int c2 = col[e + 4 + half];
        int c3 = col[e + 6 + half];
        unsigned int p0 = xs2[(size_t)c0 * 32 + sl];
        unsigned int p1 = xs2[(size_t)c1 * 32 + sl];
        unsigned int p2 = xs2[(size_t)c2 * 32 + sl];
        unsigned int p3 = xs2[(size_t)c3 * 32 + sl];
        ax += bf_lo(p0); ay += bf_hi(p0);
        ax += bf_lo(p1); ay += bf_hi(p1);
        ax += bf_lo(p2); ay += bf_hi(p2);
        ax += bf_lo(p3); ay += bf_hi(p3);
    }
    for (; e < end; e += 2) {
        if (e + half < end) {
            int c = col[e + half];
            unsigned int p = xs2[(size_t)c * 32 + sl];
            ax += bf_lo(p);
            ay += bf_hi(p);
        }
    }
    ax += __shfl_xor(ax, 32);
    ay += __shfl_xor(ay, 32);
    if (half == 0) {
        out2[(size_t)i * 32 + sl] = pack2bf(di * ax, di * ay);
    }
}

// layer 2: 128 feats = 32 lanes x uint2 (4 bf16); 8 rows in flight per wave
__global__ __launch_bounds__(256)
void agg128_bf16_kernel(const uint2* __restrict__ xs4, const int* __restrict__ rowptr,
                        const int* __restrict__ col, const float* __restrict__ dinv,
                        uint2* __restrict__ out4, int n) {
    int wid = (blockIdx.x * 256 + threadIdx.x) >> 6;
    int lane = threadIdx.x & 63;
    if (wid >= n) return;
    int i = __builtin_amdgcn_readfirstlane(wid);
    int half = lane >> 5;
    int sl = lane & 31;
    int beg = rowptr[i];
    int end = rowptr[i + 1];
    float di = dinv[i];
    float a0 = 0.0f, a1 = 0.0f, a2 = 0.0f, a3 = 0.0f;
    if (half == 0) {
        uint2 sp = xs4[(size_t)i * 32 + sl];
        a0 = bf_lo(sp.x); a1 = bf_hi(sp.x);
        a2 = bf_lo(sp.y); a3 = bf_hi(sp.y);
    }
    int e = beg;
    for (; e + 7 < end; e += 8) {
        int c0 = col[e + half];
        int c1 = col[e + 2 + half];
        int c2 = col[e + 4 + half];
        int c3 = col[e + 6 + half];
        uint2 p0 = xs4[(size_t)c0 * 32 + sl];
        uint2 p1 = xs4[(size_t)c1 * 32 + sl];
        uint2 p2 = xs4[(size_t)c2 * 32 + sl];
        uint2 p3 = xs4[(size_t)c3 * 32 + sl];
        a0 += bf_lo(p0.x); a1 += bf_hi(p0.x); a2 += bf_lo(p0.y); a3 += bf_hi(p0.y);
        a0 += bf_lo(p1.x); a1 += bf_hi(p1.x); a2 += bf_lo(p1.y); a3 += bf_hi(p1.y);
        a0 += bf_lo(p2.x); a1 += bf_hi(p2.x); a2 += bf_lo(p2.y); a3 += bf_hi(p2.y);
        a0 += bf_lo(p3.x); a1 += bf_hi(p3.x); a2 += bf_lo(p3.y); a3 += bf_hi(p3.y);
    }
    for (; e < end; e += 2) {
        if (e + half < end) {
            int c = col[e + half];
            uint2 p = xs4[(size_t)c * 32 + sl];
            a0 += bf_lo(p.x); a1 += bf_hi(p.x);
            a2 += bf_lo(p.y); a3 += bf_hi(p.y);
        }
    }
    a0 += __shfl_xor(a0, 32);
    a1 += __shfl_xor(a1, 32);
    a2 += __shfl_xor(a2, 32);
    a3 += __shfl_xor(a3, 32);
    if (half == 0) {
        uint2 o;
        o.x = pack2bf(di * a0, di * a1);
        o.y = pack2bf(di * a2, di * a3);
        out4[(size_t)i * 32 + sl] = o;
    }
}

// ---------------- MFMA GEMM: C[n,128] = A[n,K](bf16) @ W[K,128](fp32->bf16) + b ----------------
// DSCALE: epilogue multiplies by dinv[row] (producing prescaled hs for layer-2 agg).
// mfma_f32_16x16x32_bf16: A-frag lane l: row=l&15, k=(l>>4)*8+j ; B-frag: col=l&15, k=(l>>4)*8+j ;
// C/D: col=lane&15, row=(lane>>4)*4+reg  [m89-verified].

template <int K, int BF16OUT, int DSCALE>
__global__ __launch_bounds__(256)
void gemm_mfma_kernel(const unsigned short* __restrict__ A, const float* __restrict__ W,
                      const float* __restrict__ bias, const float* __restrict__ dinv,
                      void* __restrict__ C, int n, int ntiles, int do_relu) {
    constexpr int KK = K / 32;
    __shared__ short sB[8 * KK * 64 * 8];  // = K*128 bf16, frag-major
    int t = threadIdx.x;
    constexpr int total = 8 * KK * 64 * 8;
    for (int e = t; e < total; e += 256) {
        int j = e & 7;
        int l = (e >> 3) & 63;
        int rest = e >> 9;          // c*KK + kk
        int kk = rest % KK;
        int c = rest / KK;
        int rk = kk * 32 + (l >> 4) * 8 + j;
        int cc = c * 16 + (l & 15);
        sB[e] = (short)f2bf(W[rk * 128 + cc]);
    }
    __syncthreads();

    int wid = t >> 6;
    int l = t & 63;
    int tile = blockIdx.x * 4 + wid;
    if (tile >= ntiles) return;
    int r0 = tile * 16;

    const short8v* sB8 = (const short8v*)sB;
    f32x4 acc[8];
#pragma unroll
    for (int c = 0; c < 8; ++c) acc[c] = (f32x4){0.0f, 0.0f, 0.0f, 0.0f};

    int arow = r0 + (l & 15);
    if (arow >= n) arow = n - 1;  // clamp (guard at store)
#pragma unroll
    for (int kk = 0; kk < KK; ++kk) {
        short8v av = *(const short8v*)(A + (size_t)arow * K + kk * 32 + (l >> 4) * 8);
#pragma unroll
        for (int c = 0; c < 8; ++c) {
            acc[c] = __builtin_amdgcn_mfma_f32_16x16x32_bf16(av, sB8[(c * KK + kk) * 64 + l],
                                                             acc[c], 0, 0, 0);
        }
    }

    int colbase = l & 15;
    int rowg = (l >> 4) * 4;
    float dvj[4] = {1.0f, 1.0f, 1.0f, 1.0f};
    if (DSCALE) {
#pragma unroll
        for (int j = 0; j < 4; ++j) {
            int row = r0 + rowg + j;
            dvj[j] = (row < n) ? dinv[row] : 1.0f;
        }
    }
#pragma unroll
    for (int c = 0; c < 8; ++c) {
        float bv = bias[c * 16 + colbase];
#pragma unroll
        for (int j = 0; j < 4; ++j) {
            int row = r0 + rowg + j;
            if (row < n) {
                float v = acc[c][j] + bv;
                if (do_relu) v = fmaxf(v, 0.0f);
                if (DSCALE) v *= dvj[j];
                if (BF16OUT)
                    ((unsigned short*)C)[(size_t)row * 128 + c * 16 + colbase] = f2bf(v);
                else
                    ((float*)C)[(size_t)row * 128 + c * 16 + colbase] = v;
            }
        }
    }
}

// ---------------- launch ----------------

extern "C" void kernel_launch(void* const* d_in, const int* in_sizes, int n_in,
                              void* d_out, int out_size, void* d_ws, size_t ws_size,
                              hipStream_t stream) {
    const float* z  = (const float*)d_in[0];
    const int*   ei = (const int*)d_in[1];
    const float* W1 = (const float*)d_in[2];
    const float* b1 = (const float*)d_in[3];
    const float* W2 = (const float*)d_in[4];
    const float* b2 = (const float*)d_in[5];
    float* out = (float*)d_out;

    int N = in_sizes[0] / 64;
    int E = in_sizes[1] / 2;
    const int* srcp = ei;
    const int* dstp = ei + E;

    char* w = (char*)d_ws;
    auto alloc = [&](size_t bytes) -> char* {
        char* p = w;
        w += (bytes + 255) & ~(size_t)255;
        return p;
    };
    int nb = (N + 255) / 256;  // 196 for N=50000 (must be <= 256)

    int*   rowptr = (int*)alloc((size_t)(N + 1) * 4);
    float* dinv   = (float*)alloc((size_t)N * 4);
    int*   bcur   = (int*)alloc((size_t)nb * 4);
    int*   col    = (int*)alloc((size_t)E * 4);
    int2*  tmp    = (int2*)alloc((size_t)nb * BCAP * 8);
    unsigned int*   zsb = (unsigned int*)alloc((size_t)N * 64 * 2);     // bf16 zs = dinv*z (packed)
    unsigned short* a1b = (unsigned short*)alloc((size_t)N * 64 * 2);   // bf16 a1
    unsigned short* hsb = (unsigned short*)alloc((size_t)N * 128 * 2);  // bf16 hs = dinv*h
    unsigned int*   a2b = (unsigned int*)alloc((size_t)N * 128 * 2);    // bf16 a2 (packed pairs)

    // CSR build + prescaled z (3 dispatches)
    prep_kernel<<<1, 256, 0, stream>>>(bcur, nb);
    partA_kernel<<<(E + 4095) / 4096, 1024, 0, stream>>>(srcp, dstp, bcur, tmp, E);
    bucket_build_kernel<<<nb, 256, 0, stream>>>(tmp, bcur, z, rowptr, dinv, col, zsb, N, nb, E);

    int aggBlocks = (int)(((size_t)N * 64 + 255) / 256);
    int ntiles = (N + 15) / 16;           // 3125 for N=50000
    int gemmBlocks = (ntiles + 3) / 4;    // 4 waves (tiles) per block

    // layer 1: a1b = bf16(Agg(zs)) [N,64]; hsb = bf16(dinv .* relu(a1b @ W1 + b1)) [N,128]
    agg64_kernel<<<aggBlocks, 256, 0, stream>>>(zsb, rowptr, col, dinv, (unsigned int*)a1b, N);
    gemm_mfma_kernel<64, 1, 1><<<gemmBlocks, 256, 0, stream>>>(a1b, W1, b1, dinv, (void*)hsb, N, ntiles, 1);

    // layer 2: a2b = bf16(Agg(hs)) [N,128]; out = a2b @ W2 + b2 (fp32)
    agg128_bf16_kernel<<<aggBlocks, 256, 0, stream>>>((const uint2*)hsb, rowptr, col, dinv,
                                                      (uint2*)a2b, N);
    gemm_mfma_kernel<128, 0, 0><<<gemmBlocks, 256, 0, stream>>>((const unsigned short*)a2b, W2, b2, dinv,
                                                                (void*)out, N, ntiles, 0);
}